// Round 10
// baseline (100.507 us; speedup 1.0000x reference)
//
#include <hip/hip_runtime.h>

// FusedSOSCascade: 8-section biquad cascade, C=128, T=65536, fp32.
// R12 (resubmit; R9-round infra failure, kernel never ran).
// Delete staging. R10->R11 null result (87.47 -> 87.44us despite 3x
// fewer phase-2 LDS instrs) proves the MFMA/LDS phase is NOT the cost; the
// remaining ~25us kernel is the staging pipeline + phase-locked structure
// (2 blocks/CU, all in stage->barrier->compute lockstep) + per-block h.
//  1. B-fragments straight from global: 8 contiguous fp32/lane (2 dwordx4)
//     + in-register fp16 cvt. Toeplitz re-reads (4-5x) are L2-served
//     (block working set ~100KB << 4MB). Deletes ds_writes, staging cvt,
//     38KB LDS, and the barrier.
//  2. h + A-fragment table built ONCE by a 1-block pre-kernel into d_ws
//     (5120B); main kernel waves load afrag via 5 dwordx4 (L2/L3-hit).
//     Stream-ordered, no sync needed.
//  3. No LDS, no barrier, VGPR<=128 -> 1024 blocks x 4 waves self-stagger;
//     pure load->MFMA->store stream at >=16 waves/CU.
// Fragment math (R9-verified): A_m[j][kk]=h(j+128-32m-kk); B lane l
// (r=l&15,g=l>>4) reads x[c0+r][tau-128+32m+8g .. +7]; rotation identity
// frag(lt+2,m)==frag(lt,m+1) -> 2 chains, 1 new fragment each per tile.
// OOB: offsets are %8==0 so chunks are fully in/out of [0,T); out-of-range
// chunks only ever multiply h-taps that are structurally zero -> zero-fill
// is EXACT (true zero-state response).

#define T_LEN 65536
#define NTAP  144
#define TPB   256

typedef _Float16 half8 __attribute__((ext_vector_type(8)));
typedef float    f32x4 __attribute__((ext_vector_type(4)));

// ---- Pre-kernel: systolic exact h (lane k = section k, DPP row_shr:1
// daisy-chain, R10/R11-verified) + A-fragment table -> workspace.
__global__ __launch_bounds__(64)
void FusedSOS_hbuild(const float* __restrict__ sos,
                     _Float16* __restrict__ atab) {
  __shared__ float hs[NTAP];
  const int tid = threadIdx.x;            // one wave
  const int k = tid & 7;
  const float a0  = sos[k * 6 + 3];
  const float cb0 =  sos[k * 6 + 0] / a0;
  const float cb1 =  sos[k * 6 + 1] / a0;
  const float cb2 =  sos[k * 6 + 2] / a0;
  const float cn1 = -(sos[k * 6 + 4] / a0);
  const float cn2 = -(sos[k * 6 + 5] / a0);
  float y = 0.f, z1 = 0.f, z2 = 0.f;
#pragma unroll 4
  for (int n = 0; n < NTAP + 7; ++n) {
    const int ui = __builtin_amdgcn_update_dpp(0, __float_as_int(y),
                                               0x111, 0xf, 0xf, true);
    float s = __int_as_float(ui);
    if (tid == 0) s = (n == 0) ? 1.f : 0.f;
    y  = fmaf(cb0, s, z1);
    z1 = fmaf(cb1, s, fmaf(cn1, y, z2));
    z2 = fmaf(cb2, s, cn2 * y);
    if (tid == 7 && n >= 7) hs[n - 7] = y;
  }
  asm volatile("s_waitcnt lgkmcnt(0)" ::: "memory");   // single-wave LDS sync
  const int r = tid & 15, g = tid >> 4;
#pragma unroll
  for (int m = 0; m < 5; ++m) {
    half8 af;
#pragma unroll
    for (int e = 0; e < 8; ++e) {
      const int i = r + 128 - 32 * m - 8 * g - e;
      af[e] = (_Float16)((i >= 0 && i < NTAP) ? hs[i] : 0.f);
    }
    *(half8*)(&atab[(tid * 5 + m) * 8]) = af;
  }
}

// Load fragment at sample offset OFF (multiple of 8) from row xr, fp32 ->
// fp16 (RTN, identical to the staged conversion). Whole-chunk predication.
#define LOADF(dst, OFF)                                                      \
  do {                                                                       \
    const int off_ = (OFF);                                                  \
    float4 aa = make_float4(0.f, 0.f, 0.f, 0.f);                             \
    float4 bb = make_float4(0.f, 0.f, 0.f, 0.f);                             \
    if (off_ >= 0 && off_ < T_LEN) {                                         \
      aa = *(const float4*)(xr + off_);                                      \
      bb = *(const float4*)(xr + off_ + 4);                                  \
    }                                                                        \
    (dst) = (half8){(_Float16)aa.x, (_Float16)aa.y, (_Float16)aa.z,          \
                    (_Float16)aa.w, (_Float16)bb.x, (_Float16)bb.y,          \
                    (_Float16)bb.z, (_Float16)bb.w};                         \
  } while (0)

__global__ __launch_bounds__(TPB, 4)
void FusedSOSCascade_20040317403806_kernel(const float* __restrict__ x,
                                           const _Float16* __restrict__ atab,
                                           float* __restrict__ out) {
  const int tid = threadIdx.x;            // 0..255, 4 waves
  const int wv  = tid >> 6;
  const int l   = tid & 63;
  const int r   = l & 15;                 // B col c / D col c
  const int g   = l >> 4;                 // k-group / D row-group
  const int cgi = blockIdx.x >> 7;        // 0..7  channel group
  const int tb  = blockIdx.x & 127;       // 0..127 time block (512 samples)
  const int c0  = cgi * 16;
  const int tstart = tb * 512 + wv * 128; // wave's 128-sample region

  const float* xr = x + (size_t)(c0 + r) * T_LEN;

  // A fragments from the precomputed table (L2/L3-hit after first block).
  half8 afrag[5];
#pragma unroll
  for (int m = 0; m < 5; ++m)
    afrag[m] = *(const half8*)(&atab[(l * 5 + m) * 8]);

  // Even/odd chains over 8 tiles: E=frag(2q,m), O=frag(2q+1,m).
  const int base = tstart + 8 * g - 128;
  half8 E[5], O[5];
#pragma unroll
  for (int m = 0; m < 5; ++m) LOADF(E[m], base + 32 * m);
#pragma unroll
  for (int m = 0; m < 5; ++m) LOADF(O[m], base + 16 + 32 * m);

  float* orow = out + (size_t)(c0 + r) * T_LEN + tstart;
#pragma unroll
  for (int q = 0; q < 4; ++q) {
    half8 nE, nO;
    if (q < 3) {                          // issue next-slot loads early
      LOADF(nE, base + 160 + 32 * q);     // frag(2q+2, m=4)
      LOADF(nO, base + 176 + 32 * q);     // frag(2q+3, m=4)
    }
    f32x4 accE = {0.f, 0.f, 0.f, 0.f};
    f32x4 accO = {0.f, 0.f, 0.f, 0.f};
#pragma unroll
    for (int m = 0; m < 5; ++m) {
      accE = __builtin_amdgcn_mfma_f32_16x16x32_f16(afrag[m], E[m], accE,
                                                    0, 0, 0);
      accO = __builtin_amdgcn_mfma_f32_16x16x32_f16(afrag[m], O[m], accO,
                                                    0, 0, 0);
    }
    // D[row=4g+reg][col=r] -> out[c0+r][tstart + 16*lt + 4g + reg]
    *(float4*)(orow + 32 * q + 4 * g) =
        make_float4(accE[0], accE[1], accE[2], accE[3]);
    *(float4*)(orow + 32 * q + 16 + 4 * g) =
        make_float4(accO[0], accO[1], accO[2], accO[3]);
    if (q < 3) {
#pragma unroll
      for (int m = 0; m < 4; ++m) { E[m] = E[m + 1]; O[m] = O[m + 1]; }
      E[4] = nE; O[4] = nO;
    }
  }
}

extern "C" void kernel_launch(void* const* d_in, const int* in_sizes, int n_in,
                              void* d_out, int out_size, void* d_ws, size_t ws_size,
                              hipStream_t stream) {
  const float* x   = (const float*)d_in[0];   // [128, 65536] fp32
  const float* sos = (const float*)d_in[1];   // [8, 6] fp32
  float* out = (float*)d_out;                 // [128, 65536] fp32
  _Float16* atab = (_Float16*)d_ws;           // 5120 B in workspace
  (void)in_sizes; (void)n_in; (void)out_size; (void)ws_size;

  FusedSOS_hbuild<<<dim3(1), dim3(64), 0, stream>>>(sos, atab);
  FusedSOSCascade_20040317403806_kernel<<<dim3(1024), dim3(TPB), 0, stream>>>(
      x, atab, out);
}

// Round 11
// 97.692 us; speedup vs baseline: 1.0288x; 1.0288x over previous
//
#include <hip/hip_runtime.h>

// FusedSOSCascade: 8-section biquad cascade, C=128, T=65536, fp32.
// R13: R12 regressed 87.4 -> 100.5 despite identical math. Model: the
// 1-block pre-kernel is a SERIAL stream dependency (launch ~3-5us +
// single-wave 151-step DPP chain at idle clock ~4-9us) that all 1024 main
// blocks wait on -- R10/R11 never paid this because h built concurrently
// inside each block. Fix: single launch; every block's wave 0 runs the
// systolic h-build (R10/R11-verified), overlapped with the B-fragment
// global loads that ALL waves issue first (loads pend behind vmcnt while
// wave 0's VALU chain runs). One barrier; afrag via LDS atab; MFMA loop
// unchanged from R12. Per-block h cost ~1-2us, paid by all blocks
// CONCURRENTLY, not serially.
// Main kernel structure (R12): no x staging, B-fragments straight from
// global (2 dwordx4/lane, in-reg fp16 cvt; Toeplitz 4x re-read L2-served),
// even/odd register chains frag(tt+2,m)==frag(tt,m+1), no big LDS.
// Fragment math (R9-verified): A_m[j][kk]=h(j+128-32m-kk); B lane l
// (r=l&15,g=l>>4) reads x[c0+r][base+32m+8g..+7], base=tstart-128+8g.
// OOB chunks (offsets %8==0, whole-chunk predication) only multiply
// structurally-zero h-taps -> zero-fill is EXACT (zero-state response).

#define T_LEN 65536
#define NTAP  144
#define TPB   256

typedef _Float16 half8 __attribute__((ext_vector_type(8)));
typedef float    f32x4 __attribute__((ext_vector_type(4)));

// Load fragment at sample offset OFF (multiple of 8) from row xr, fp32 ->
// fp16 (RTN, identical to staged conversion). Whole-chunk predication.
#define LOADF(dst, OFF)                                                      \
  do {                                                                       \
    const int off_ = (OFF);                                                  \
    float4 aa = make_float4(0.f, 0.f, 0.f, 0.f);                             \
    float4 bb = make_float4(0.f, 0.f, 0.f, 0.f);                             \
    if (off_ >= 0 && off_ < T_LEN) {                                         \
      aa = *(const float4*)(xr + off_);                                      \
      bb = *(const float4*)(xr + off_ + 4);                                  \
    }                                                                        \
    (dst) = (half8){(_Float16)aa.x, (_Float16)aa.y, (_Float16)aa.z,          \
                    (_Float16)aa.w, (_Float16)bb.x, (_Float16)bb.y,          \
                    (_Float16)bb.z, (_Float16)bb.w};                         \
  } while (0)

__global__ __launch_bounds__(TPB, 4)
void FusedSOSCascade_20040317403806_kernel(const float* __restrict__ x,
                                           const float* __restrict__ sos,
                                           float* __restrict__ out) {
  __shared__ float hs[NTAP];                        // 576 B
  __shared__ alignas(16) _Float16 atab[64 * 5 * 8]; // 5120 B

  const int tid = threadIdx.x;            // 0..255, 4 waves
  const int wv  = tid >> 6;
  const int l   = tid & 63;
  const int r   = l & 15;                 // B col c / D col c
  const int g   = l >> 4;                 // k-group / D row-group
  const int cgi = blockIdx.x >> 7;        // 0..7  channel group
  const int tb  = blockIdx.x & 127;       // 0..127 time block (512 samples)
  const int c0  = cgi * 16;
  const int tstart = tb * 512 + wv * 128; // wave's 128-sample region

  const float* xr = x + (size_t)(c0 + r) * T_LEN;

  // ---- Issue B-fragment loads FIRST in all waves: they pend behind vmcnt
  // while wave 0 runs the h-build chain (VALU-only, doesn't wait on vmem).
  const int base = tstart + 8 * g - 128;
  half8 E[5], O[5];
#pragma unroll
  for (int m = 0; m < 5; ++m) LOADF(E[m], base + 32 * m);
#pragma unroll
  for (int m = 0; m < 5; ++m) LOADF(O[m], base + 16 + 32 * m);

  if (tid < 64) {
    // ---- Wave 0: systolic exact h (lane k = section k&7; DPP row_shr:1
    // daisy-chain passes y downstream; lane 0 injects delta; lane 7 emits
    // h). Numerically identical to reference cascade on an impulse.
    const int k = tid & 7;
    {
      const float a0  = sos[k * 6 + 3];
      const float cb0 =  sos[k * 6 + 0] / a0;
      const float cb1 =  sos[k * 6 + 1] / a0;
      const float cb2 =  sos[k * 6 + 2] / a0;
      const float cn1 = -(sos[k * 6 + 4] / a0);
      const float cn2 = -(sos[k * 6 + 5] / a0);
      float y = 0.f, z1 = 0.f, z2 = 0.f;
#pragma unroll 4
      for (int n = 0; n < NTAP + 7; ++n) {
        const int ui = __builtin_amdgcn_update_dpp(0, __float_as_int(y),
                                                   0x111, 0xf, 0xf, true);
        float s = __int_as_float(ui);
        if (tid == 0) s = (n == 0) ? 1.f : 0.f;
        y  = fmaf(cb0, s, z1);
        z1 = fmaf(cb1, s, fmaf(cn1, y, z2));
        z2 = fmaf(cb2, s, cn2 * y);
        if (tid == 7 && n >= 7) hs[n - 7] = y;
      }
    }
    asm volatile("s_waitcnt lgkmcnt(0)" ::: "memory"); // wave-local LDS sync
    // ---- A-fragment table: lane ll holds afrag[m][e] =
    // h(rr + 128 - 32m - 8gg - e), rr=ll&15, gg=ll>>4. 5 x 16B per lane.
    {
      const int rr = tid & 15, gg = tid >> 4;
#pragma unroll
      for (int m = 0; m < 5; ++m) {
        half8 af;
#pragma unroll
        for (int e = 0; e < 8; ++e) {
          const int i = rr + 128 - 32 * m - 8 * gg - e;
          af[e] = (_Float16)((i >= 0 && i < NTAP) ? hs[i] : 0.f);
        }
        *(half8*)(&atab[(tid * 5 + m) * 8]) = af;
      }
    }
  }
  __syncthreads();

  // ---- A fragments from LDS table (5 x ds_read_b128).
  half8 afrag[5];
#pragma unroll
  for (int m = 0; m < 5; ++m)
    afrag[m] = *(const half8*)(&atab[(l * 5 + m) * 8]);

  float* orow = out + (size_t)(c0 + r) * T_LEN + tstart;

  // ---- Even/odd chains over 8 tiles: E=frag(2q,m), O=frag(2q+1,m);
  // rotation identity frag(tt+2,m)==frag(tt,m+1) -> 1 new fragment per
  // tile per chain.
#pragma unroll
  for (int q = 0; q < 4; ++q) {
    half8 nE, nO;
    if (q < 3) {                          // issue next-slot loads early
      LOADF(nE, base + 160 + 32 * q);     // frag(2q+2, m=4)
      LOADF(nO, base + 176 + 32 * q);     // frag(2q+3, m=4)
    }
    f32x4 accE = {0.f, 0.f, 0.f, 0.f};
    f32x4 accO = {0.f, 0.f, 0.f, 0.f};
#pragma unroll
    for (int m = 0; m < 5; ++m) {
      accE = __builtin_amdgcn_mfma_f32_16x16x32_f16(afrag[m], E[m], accE,
                                                    0, 0, 0);
      accO = __builtin_amdgcn_mfma_f32_16x16x32_f16(afrag[m], O[m], accO,
                                                    0, 0, 0);
    }
    // D[row=4g+reg][col=r] -> out[c0+r][tstart + 16*lt + 4g + reg]
    *(float4*)(orow + 32 * q + 4 * g) =
        make_float4(accE[0], accE[1], accE[2], accE[3]);
    *(float4*)(orow + 32 * q + 16 + 4 * g) =
        make_float4(accO[0], accO[1], accO[2], accO[3]);
    if (q < 3) {
#pragma unroll
      for (int m = 0; m < 4; ++m) { E[m] = E[m + 1]; O[m] = O[m + 1]; }
      E[4] = nE; O[4] = nO;
    }
  }
}

extern "C" void kernel_launch(void* const* d_in, const int* in_sizes, int n_in,
                              void* d_out, int out_size, void* d_ws, size_t ws_size,
                              hipStream_t stream) {
  const float* x   = (const float*)d_in[0];   // [128, 65536] fp32
  const float* sos = (const float*)d_in[1];   // [8, 6] fp32
  float* out = (float*)d_out;                 // [128, 65536] fp32
  (void)in_sizes; (void)n_in; (void)out_size; (void)d_ws; (void)ws_size;

  FusedSOSCascade_20040317403806_kernel<<<dim3(1024), dim3(TPB), 0, stream>>>(
      x, sos, out);
}

// Round 12
// 87.991 us; speedup vs baseline: 1.1422x; 1.1102x over previous
//
#include <hip/hip_runtime.h>

// FusedSOSCascade: 8-section biquad cascade, C=128, T=65536, fp32.
// R14: revert to R11's staged structure (best: 87.44us; R12/R13 proved
// direct-global fragments are ~10us/kernel slower) + T14 intra-block
// stage/compute overlap:
//   tile = 16ch x 1024 samples, two halves. Stage region A [-128,536)
//   (2656 f4, waves 1-7; wave 0 = systolic h + atab). barrier. All 8
//   waves ISSUE region B [536,1056) loads (5 f4/thread, pend in VGPRs
//   behind vmcnt) -> compute half0 (4 tiles/wave; reads LDS [0,648] only)
//   -> cvt+ds_write B (disjoint range, race-free vs other waves' half0
//   reads) -> barrier -> compute half1 (reads A-tail U B).
//   Region B HBM latency hides under half0's MFMA phase.
// All arithmetic identical to R11: systolic exact h (DPP row_shr:1),
// atab A-fragments, fp16 RTN staging cvt, f32_16x16x32_f16 MFMA,
// even/odd chains frag(tt+2,m)==frag(tt,m+1), same store pattern.
// OOB staging slots zero-filled -> zero-state response exact.

#define T_LEN   65536
#define CG      16
#define TB      1024
#define NTAP    144
#define HALO    128
#define XSPAN   (HALO + TB + 32)          // 1184 samples per row
#define XSTRIDE 1192                      // fp16 units, 16B-aligned rows
#define TPB     512                       // 8 waves
#define AQ      166                       // region A float4 cols [0,166)
#define BQ      130                       // region B float4 cols [166,296)
#define NA4     (CG * AQ)                 // 2656
#define NB4     (CG * BQ)                 // 2080
#define NSTAGE  (TPB - 64)                // 448 region-A staging threads

typedef _Float16 half8  __attribute__((ext_vector_type(8)));
typedef _Float16 half4h __attribute__((ext_vector_type(4)));
typedef float    f32x4  __attribute__((ext_vector_type(4)));

__global__ __launch_bounds__(TPB)
void FusedSOSCascade_20040317403806_kernel(const float* __restrict__ x,
                                           const float* __restrict__ sos,
                                           float* __restrict__ out) {
  __shared__ alignas(16) _Float16 lds_x[CG * XSTRIDE];   // 38144 B
  __shared__ float hs[NTAP];                             // 576 B
  __shared__ alignas(16) _Float16 atab[64 * 5 * 8];      // 5120 B

  const int tid = threadIdx.x;            // 0..511
  const int cg  = blockIdx.x & 7;
  const int tb  = blockIdx.x >> 3;        // 0..63
  const int c0  = cg * CG;
  const int t0  = tb * TB;

  // ---- Phase 1: wave 0 h-build; waves 1-7 stage region A.
  if (tid < 64) {
    const int k = tid & 7;
    {
      const float a0  = sos[k * 6 + 3];
      const float cb0 =  sos[k * 6 + 0] / a0;
      const float cb1 =  sos[k * 6 + 1] / a0;
      const float cb2 =  sos[k * 6 + 2] / a0;
      const float cn1 = -(sos[k * 6 + 4] / a0);
      const float cn2 = -(sos[k * 6 + 5] / a0);
      float y = 0.f, z1 = 0.f, z2 = 0.f;
#pragma unroll 4
      for (int n = 0; n < NTAP + 7; ++n) {
        const int ui = __builtin_amdgcn_update_dpp(0, __float_as_int(y),
                                                   0x111, 0xf, 0xf, true);
        float s = __int_as_float(ui);
        if (tid == 0) s = (n == 0) ? 1.f : 0.f;
        y  = fmaf(cb0, s, z1);
        z1 = fmaf(cb1, s, fmaf(cn1, y, z2));
        z2 = fmaf(cb2, s, cn2 * y);
        if (tid == 7 && n >= 7) hs[n - 7] = y;
      }
    }
    asm volatile("s_waitcnt lgkmcnt(0)" ::: "memory");
    {
      const int rr = tid & 15, gg = tid >> 4;
#pragma unroll
      for (int m = 0; m < 5; ++m) {
        half8 af;
#pragma unroll
        for (int e = 0; e < 8; ++e) {
          const int i = rr + 128 - 32 * m - 8 * gg - e;
          af[e] = (_Float16)((i >= 0 && i < NTAP) ? hs[i] : 0.f);
        }
        *(half8*)(&atab[(tid * 5 + m) * 8]) = af;
      }
    }
  } else {
    const int st = tid - 64;              // 0..447
    float4 v[6];
#pragma unroll
    for (int k = 0; k < 6; ++k) {
      const int idx = st + k * NSTAGE;
      float4 t = make_float4(0.f, 0.f, 0.f, 0.f);
      if (idx < NA4) {
        const int row = idx / AQ;
        const int c4  = idx - row * AQ;
        const int gt  = t0 - HALO + 4 * c4;
        if (gt >= 0 && gt < T_LEN)
          t = *(const float4*)(x + (size_t)(c0 + row) * T_LEN + gt);
      }
      v[k] = t;
    }
#pragma unroll
    for (int k = 0; k < 6; ++k) {
      const int idx = st + k * NSTAGE;
      if (idx < NA4) {
        const int row = idx / AQ;
        const int c4  = idx - row * AQ;
        half4h hv = { (_Float16)v[k].x, (_Float16)v[k].y,
                      (_Float16)v[k].z, (_Float16)v[k].w };
        *(half4h*)(&lds_x[row * XSTRIDE + 4 * c4]) = hv;
      }
    }
  }
  __syncthreads();

  // ---- Phase 2a: all waves issue region B loads (held in VGPRs).
  float4 vb[5];
#pragma unroll
  for (int k = 0; k < 5; ++k) {
    const int idx = tid + k * TPB;
    float4 t = make_float4(0.f, 0.f, 0.f, 0.f);
    if (idx < NB4) {
      const int row = idx / BQ;
      const int j   = idx - row * BQ;
      const int gt  = t0 - HALO + 4 * (AQ + j);   // = t0+536+4j >= 0
      if (gt < T_LEN)
        t = *(const float4*)(x + (size_t)(c0 + row) * T_LEN + gt);
    }
    vb[k] = t;
  }

  // ---- MFMA setup.
  const int wv = tid >> 6;                // 0..7
  const int l  = tid & 63;
  const int r  = l & 15;                  // B col c / D col c
  const int g  = l >> 4;                  // k-group / D row-group

  half8 afrag[5];
#pragma unroll
  for (int m = 0; m < 5; ++m)
    afrag[m] = *(const half8*)(&atab[(l * 5 + m) * 8]);

#define XFRAG(tt, m) \
  (*(const half8*)(&lds_x[r * XSTRIDE + 16 * (tt) + 32 * (m) + 8 * g]))

  float* orow = out + (size_t)(c0 + r) * T_LEN + t0;

  // 4 tiles per wave per half, even/odd register chains.
#define COMPUTE_HALF(TT0)                                                    \
  do {                                                                       \
    const int tt0 = (TT0);                                                   \
    half8 E[5], O[5];                                                        \
    _Pragma("unroll")                                                        \
    for (int m = 0; m < 5; ++m) E[m] = XFRAG(tt0, m);                        \
    _Pragma("unroll")                                                        \
    for (int m = 0; m < 5; ++m) O[m] = XFRAG(tt0 + 1, m);                    \
    _Pragma("unroll")                                                        \
    for (int q = 0; q < 2; ++q) {                                            \
      half8 nE, nO;                                                          \
      if (q == 0) { nE = XFRAG(tt0 + 2, 4); nO = XFRAG(tt0 + 3, 4); }        \
      f32x4 accE = {0.f, 0.f, 0.f, 0.f};                                     \
      f32x4 accO = {0.f, 0.f, 0.f, 0.f};                                     \
      _Pragma("unroll")                                                      \
      for (int m = 0; m < 5; ++m) {                                          \
        accE = __builtin_amdgcn_mfma_f32_16x16x32_f16(afrag[m], E[m], accE,  \
                                                      0, 0, 0);              \
        accO = __builtin_amdgcn_mfma_f32_16x16x32_f16(afrag[m], O[m], accO,  \
                                                      0, 0, 0);              \
      }                                                                      \
      const int ttE = tt0 + 2 * q;                                           \
      *(float4*)(orow + 16 * ttE + 4 * g) =                                  \
          make_float4(accE[0], accE[1], accE[2], accE[3]);                   \
      *(float4*)(orow + 16 * (ttE + 1) + 4 * g) =                            \
          make_float4(accO[0], accO[1], accO[2], accO[3]);                   \
      if (q == 0) {                                                          \
        _Pragma("unroll")                                                    \
        for (int m = 0; m < 4; ++m) { E[m] = E[m + 1]; O[m] = O[m + 1]; }    \
        E[4] = nE; O[4] = nO;                                                \
      }                                                                      \
    }                                                                        \
  } while (0)

  // ---- Half 0: tiles wv*4 .. wv*4+3 (LDS reads within [0,648] = region A).
  COMPUTE_HALF(wv * 4);

  // ---- Write region B (disjoint fp16 range [664,1184) -- race-free with
  // any wave still reading half-0's [0,648]).
#pragma unroll
  for (int k = 0; k < 5; ++k) {
    const int idx = tid + k * TPB;
    if (idx < NB4) {
      const int row = idx / BQ;
      const int j   = idx - row * BQ;
      half4h hv = { (_Float16)vb[k].x, (_Float16)vb[k].y,
                    (_Float16)vb[k].z, (_Float16)vb[k].w };
      *(half4h*)(&lds_x[row * XSTRIDE + 4 * (AQ + j)]) = hv;
    }
  }
  __syncthreads();

  // ---- Half 1: tiles 32 + wv*4 .. +3 (reads A-tail U B, all staged).
  COMPUTE_HALF(32 + wv * 4);

#undef COMPUTE_HALF
#undef XFRAG
}

extern "C" void kernel_launch(void* const* d_in, const int* in_sizes, int n_in,
                              void* d_out, int out_size, void* d_ws, size_t ws_size,
                              hipStream_t stream) {
  const float* x   = (const float*)d_in[0];   // [128, 65536] fp32
  const float* sos = (const float*)d_in[1];   // [8, 6] fp32
  float* out = (float*)d_out;                 // [128, 65536] fp32
  (void)in_sizes; (void)n_in; (void)out_size; (void)d_ws; (void)ws_size;

  FusedSOSCascade_20040317403806_kernel<<<dim3(512), dim3(TPB), 0, stream>>>(
      x, sos, out);
}